// Round 1
// baseline (469.122 us; speedup 1.0000x reference)
//
#include <hip/hip_runtime.h>
#include <cstdint>

// Problem constants (from reference): N=8, C=3, H=720, W=1280
constexpr int N_ = 8;
constexpr int C_ = 3;
constexpr int H_ = 720;
constexpr int W_ = 1280;
constexpr int HW = H_ * W_;

constexpr int TW = 128;          // target tile width  (cols)
constexpr int TH = 64;           // target tile height (rows)
constexpr int M_ = 64;           // max handled |trunc(disp)|; beyond -> outlier list
                                 // flow ~ N(0,20): P(|d|>64) ~ 2*Phi(-3.25) => ~2.1K outliers/batch
constexpr int NTX = W_ / TW;                 // 10
constexpr int NTY = (H_ + TH - 1) / TH;      // 12 (last tile = 16 rows)
constexpr int BLK = 512;
constexpr int OSEG = 16384;      // per-batch outlier capacity (~7.7x expected)

typedef float vf4 __attribute__((ext_vector_type(4)));

struct Outlier { unsigned long long key; int tgt; int pad; };  // 16 B

// key = (bits(v) << 32) | (p+1);  v = fx*fx+fy*fy >= 0 so IEEE bits preserve
// order; low 32 bits implement "larger source index wins ties" (reference's
// stable ascending argsort -> max rank wins). key==0 <=> hole.
__device__ __forceinline__ unsigned long long make_key(float fx, float fy, int p) {
    // exact mul-mul-add in fp32, no FMA contraction (must match numpy bits)
    float v = __fadd_rn(__fmul_rn(fx, fx), __fmul_rn(fy, fy));
    return ((unsigned long long)__float_as_uint(v) << 32) | (unsigned int)(p + 1);
}

// K0: collect rare large-displacement sources into per-batch compact lists.
__global__ __launch_bounds__(256) void outlier_kernel(
    const float* __restrict__ flow,
    unsigned long long* __restrict__ ocnt,
    Outlier* __restrict__ olist) {
    int idx = blockIdx.x * 256 + threadIdx.x;     // over N_*HW/4 float4 groups
    int n = idx / (HW / 4);
    int p0 = (idx - n * (HW / 4)) * 4;
    const float* f = flow + (size_t)n * 2 * HW;
    vf4 fx4 = *(const vf4*)(f + p0);
    vf4 fy4 = *(const vf4*)(f + HW + p0);
    float fxs[4] = {fx4.x, fx4.y, fx4.z, fx4.w};
    float fys[4] = {fy4.x, fy4.y, fy4.z, fy4.w};
    int y = p0 / W_;
    int x0 = p0 - y * W_;                         // p0 mult of 4, W%4==0: same row
    #pragma unroll
    for (int i = 0; i < 4; ++i) {
        int dx = (int)fxs[i];                     // trunc toward zero == astype(int32)
        int dy = (int)fys[i];
        if (dx > M_ || dx < -M_ || dy > M_ || dy < -M_) {
            int wx = min(max(x0 + i + dx, 0), W_ - 1);
            int wy = min(max(y + dy, 0), H_ - 1);
            unsigned long long o = atomicAdd(&ocnt[n], 1ULL);
            if (o < (unsigned long long)OSEG) {
                Outlier e;
                e.key = make_key(fxs[i], fys[i], p0 + i);
                e.tgt = wy * W_ + wx;
                e.pad = 0;
                olist[n * OSEG + o] = e;
            }
        }
    }
}

// K1: per target-tile — scan source window (tile +- M_), resolve winners via
// LDS atomicMax, apply outliers, gather image, write out.
// Block remap: n = bid&7, tile = bid>>3 (row-major). Under the round-robin
// block->XCD dispatch this pins one batch per XCD and walks its tiles in
// row-major order: one tile-row's flow window (192 x 1280 x 8B ~ 2MB) fits
// the 4MB per-XCD L2, so the 6x window overlap becomes L2 hits.
__global__ __launch_bounds__(BLK, 4) void warp_tile_kernel(
    const float* __restrict__ image,
    const float* __restrict__ flow,
    const unsigned long long* __restrict__ ocnt,
    const Outlier* __restrict__ olist,
    float* __restrict__ out) {
    __shared__ unsigned long long lkey[TH * TW];          // 64 KB -> 2 blocks/CU
    int bid = blockIdx.x;
    int n    = bid & 7;                                   // N_ == 8 == #XCDs
    int tile = bid >> 3;                                  // 0..119, row-major
    int tyi = tile / NTX;
    int txi = tile - tyi * NTX;
    int tx0 = txi * TW;
    int ty0 = tyi * TH;
    int th_eff = min(TH, H_ - ty0);                       // 16 for last tile row
    int tid = threadIdx.x;

    for (int i = tid; i < TH * TW; i += BLK) lkey[i] = 0ULL;
    __syncthreads();

    // source window: all |disp|<=M_ sources whose clipped target lands in tile.
    // wx0 is a multiple of 64 -> 16B-aligned float4 rows. Interior window width
    // is exactly 256 = 64 lanes x float4; 512 threads = 8 rows per sweep.
    int wy0 = max(0, ty0 - M_), wy1 = min(H_, ty0 + th_eff + M_);
    int wx0 = max(0, tx0 - M_), wx1 = min(W_, tx0 + TW + M_);
    const float* fx_p = flow + (size_t)n * 2 * HW;
    const float* fy_p = fx_p + HW;

    int x4   = wx0 + ((tid & 63) << 2);                   // this lane's column
    int rowg = tid >> 6;                                  // 0..7
    if (x4 < wx1) {
        #pragma unroll 2
        for (int y = wy0 + rowg; y < wy1; y += 8) {
            int pbase = y * W_ + x4;
            vf4 fx4 = *(const vf4*)(fx_p + pbase);
            vf4 fy4 = *(const vf4*)(fy_p + pbase);
            float fxs[4] = {fx4.x, fx4.y, fx4.z, fx4.w};
            float fys[4] = {fy4.x, fy4.y, fy4.z, fy4.w};
            #pragma unroll
            for (int i = 0; i < 4; ++i) {
                float fx = fxs[i], fy = fys[i];
                int wx = x4 + i + (int)fx;
                int wy = y + (int)fy;
                wx = min(max(wx, 0), W_ - 1);
                wy = min(max(wy, 0), H_ - 1);
                int lx = wx - tx0, ly = wy - ty0;
                if ((unsigned)lx < (unsigned)TW && (unsigned)ly < (unsigned)th_eff) {
                    atomicMax(&lkey[ly * TW + lx], make_key(fx, fy, pbase + i));
                }
            }
        }
    }
    __syncthreads();

    // apply this batch's outliers (|disp|>M_). Duplicates with the window pass
    // are harmless (same key, max is idempotent). List is ~2.1K entries, L2-hot.
    unsigned long long craw = ocnt[n];
    int cnt = (int)(craw > (unsigned long long)OSEG ? OSEG : craw);
    const Outlier* seg = olist + n * OSEG;
    for (int o = tid; o < cnt; o += BLK) {
        Outlier e = seg[o];
        int ey = e.tgt / W_, ex = e.tgt - ey * W_;
        int lx = ex - tx0, ly = ey - ty0;
        if ((unsigned)lx < (unsigned)TW && (unsigned)ly < (unsigned)th_eff)
            atomicMax(&lkey[ly * TW + lx], e.key);
    }
    __syncthreads();

    // gather winners' pixels and write the tile (coalesced, nontemporal).
    const float* img_n = image + (size_t)n * C_ * HW;
    float* out_n = out + (size_t)n * C_ * HW;
    int q4 = th_eff * (TW / 4);                           // float4 groups in tile
    for (int s = tid; s < q4; s += BLK) {
        int r = s >> 5;                                   // TW/4 == 32
        int cg = s & 31;
        int lp = r * TW + cg * 4;
        unsigned long long k0 = lkey[lp],     k1 = lkey[lp + 1];
        unsigned long long k2 = lkey[lp + 2], k3 = lkey[lp + 3];
        int s0 = (int)(unsigned int)(k0 & 0xffffffffULL) - 1;
        int s1 = (int)(unsigned int)(k1 & 0xffffffffULL) - 1;
        int s2 = (int)(unsigned int)(k2 & 0xffffffffULL) - 1;
        int s3 = (int)(unsigned int)(k3 & 0xffffffffULL) - 1;
        int op = (ty0 + r) * W_ + tx0 + cg * 4;
        #pragma unroll
        for (int c = 0; c < C_; ++c) {
            const float* pl = img_n + (size_t)c * HW;
            vf4 o;
            o.x = k0 ? pl[s0] : 0.0f;
            o.y = k1 ? pl[s1] : 0.0f;
            o.z = k2 ? pl[s2] : 0.0f;
            o.w = k3 ? pl[s3] : 0.0f;
            __builtin_nontemporal_store(o, (vf4*)(out_n + (size_t)c * HW + op));
        }
    }
}

extern "C" void kernel_launch(void* const* d_in, const int* in_sizes, int n_in,
                              void* d_out, int out_size, void* d_ws, size_t ws_size,
                              hipStream_t stream) {
    const float* image = (const float*)d_in[0];
    const float* flow  = (const float*)d_in[1];
    float* out = (float*)d_out;

    unsigned long long* ocnt = (unsigned long long*)d_ws;  // 8 counters
    Outlier* olist = (Outlier*)((char*)d_ws + 64);         // 8 x OSEG entries

    (void)hipMemsetAsync(ocnt, 0, 8 * sizeof(unsigned long long), stream);

    int k0_blocks = (N_ * HW / 4) / 256;                   // 7200
    outlier_kernel<<<k0_blocks, 256, 0, stream>>>(flow, ocnt, olist);

    warp_tile_kernel<<<N_ * NTX * NTY, BLK, 0, stream>>>(  // 960 blocks, 1D
        image, flow, ocnt, olist, out);
}

// Round 2
// 297.401 us; speedup vs baseline: 1.5774x; 1.5774x over previous
//
#include <hip/hip_runtime.h>
#include <cstdint>

// Problem constants (from reference): N=8, C=3, H=720, W=1280
constexpr int N_ = 8;
constexpr int C_ = 3;
constexpr int H_ = 720;
constexpr int W_ = 1280;
constexpr int HW = H_ * W_;

constexpr int TW = 128;          // target tile width  (cols)
constexpr int TH = 64;           // target tile height (rows)
constexpr int M_ = 64;           // max handled |trunc(disp)|; beyond -> outlier list
                                 // flow ~ N(0,20): P(|d|>64) ~ 2*Phi(-3.25) => ~2.6K outliers/batch
constexpr int NTX = W_ / TW;                 // 10
constexpr int NTY = (H_ + TH - 1) / TH;      // 12 (last tile = 16 rows)
constexpr int BLK = 512;
constexpr int OSEG = 16384;      // per-batch outlier capacity (~6x expected)
constexpr int SCAP = 128;        // per-block LDS staging capacity (expected ~3/block)
constexpr int CSTRIDE = 16;      // ULLs between per-batch counters (128 B: own L2 line)
constexpr int BPB = HW / 1024;   // K0 blocks per batch = 900 (exact)

typedef float vf4 __attribute__((ext_vector_type(4)));

struct Outlier { unsigned long long key; int tgt; int pad; };  // 16 B

// key = (bits(v) << 32) | (p+1);  v = fx*fx+fy*fy >= 0 so IEEE bits preserve
// order; low 32 bits implement "larger source index wins ties" (reference's
// stable ascending argsort -> max rank wins). key==0 <=> hole.
__device__ __forceinline__ unsigned long long make_key(float fx, float fy, int p) {
    // exact mul-mul-add in fp32, no FMA contraction (must match numpy bits)
    float v = __fadd_rn(__fmul_rn(fx, fx), __fmul_rn(fy, fy));
    return ((unsigned long long)__float_as_uint(v) << 32) | (unsigned int)(p + 1);
}

// K0: collect rare large-displacement sources into per-batch compact lists.
// Per-block LDS aggregation -> ONE global atomicAdd per block (900/batch,
// counters on separate 128B lines). Round-1 lesson: per-lane device atomics
// on a shared line serialized at ~10ns each (20K outliers -> 210us).
__global__ __launch_bounds__(256) void outlier_kernel(
    const float* __restrict__ flow,
    unsigned long long* __restrict__ ocnt,
    Outlier* __restrict__ olist) {
    __shared__ unsigned int bcnt;
    __shared__ unsigned long long gbase;
    __shared__ unsigned long long skey[SCAP];
    __shared__ int stgt[SCAP];
    if (threadIdx.x == 0) bcnt = 0;
    __syncthreads();

    int n  = blockIdx.x / BPB;                    // batch-pure blocks (900 each)
    int p0 = (blockIdx.x - n * BPB) * 1024 + threadIdx.x * 4;
    const float* f = flow + (size_t)n * 2 * HW;
    vf4 fx4 = *(const vf4*)(f + p0);
    vf4 fy4 = *(const vf4*)(f + HW + p0);
    float fxs[4] = {fx4.x, fx4.y, fx4.z, fx4.w};
    float fys[4] = {fy4.x, fy4.y, fy4.z, fy4.w};
    int y = p0 / W_;
    int x0 = p0 - y * W_;                         // p0 mult of 4, W%4==0: same row
    #pragma unroll
    for (int i = 0; i < 4; ++i) {
        int dx = (int)fxs[i];                     // trunc toward zero == astype(int32)
        int dy = (int)fys[i];
        if (dx > M_ || dx < -M_ || dy > M_ || dy < -M_) {
            int wx = min(max(x0 + i + dx, 0), W_ - 1);
            int wy = min(max(y + dy, 0), H_ - 1);
            unsigned long long key = make_key(fxs[i], fys[i], p0 + i);
            int tgt = wy * W_ + wx;
            unsigned int s = atomicAdd(&bcnt, 1u);
            if (s < (unsigned)SCAP) {
                skey[s] = key; stgt[s] = tgt;
            } else {                              // adversarial-data spill path
                unsigned long long o = atomicAdd(&ocnt[(size_t)n * CSTRIDE], 1ULL);
                if (o < (unsigned long long)OSEG) {
                    Outlier e; e.key = key; e.tgt = tgt; e.pad = 0;
                    olist[n * OSEG + (int)o] = e;
                }
            }
        }
    }
    __syncthreads();
    unsigned int c = bcnt > (unsigned)SCAP ? (unsigned)SCAP : bcnt;
    if (threadIdx.x == 0)
        gbase = c ? atomicAdd(&ocnt[(size_t)n * CSTRIDE], (unsigned long long)c)
                  : 0ULL;
    __syncthreads();
    for (unsigned int i = threadIdx.x; i < c; i += 256) {
        unsigned long long o = gbase + i;
        if (o < (unsigned long long)OSEG) {
            Outlier e; e.key = skey[i]; e.tgt = stgt[i]; e.pad = 0;
            olist[n * OSEG + (int)o] = e;
        }
    }
}

// K1: per target-tile — scan source window (tile +- M_), resolve winners via
// LDS atomicMax, apply outliers, gather image, write out.
// Block remap: n = bid&7, tile = bid>>3 (row-major). Under the round-robin
// block->XCD dispatch this pins one batch per XCD and walks its tiles in
// row-major order: one tile-row's flow window (192 x 1280 x 8B ~ 2MB) fits
// the 4MB per-XCD L2, so the 6x window overlap becomes L2 hits.
__global__ __launch_bounds__(BLK, 4) void warp_tile_kernel(
    const float* __restrict__ image,
    const float* __restrict__ flow,
    const unsigned long long* __restrict__ ocnt,
    const Outlier* __restrict__ olist,
    float* __restrict__ out) {
    __shared__ unsigned long long lkey[TH * TW];          // 64 KB -> 2 blocks/CU
    int bid = blockIdx.x;
    int n    = bid & 7;                                   // N_ == 8 == #XCDs
    int tile = bid >> 3;                                  // 0..119, row-major
    int tyi = tile / NTX;
    int txi = tile - tyi * NTX;
    int tx0 = txi * TW;
    int ty0 = tyi * TH;
    int th_eff = min(TH, H_ - ty0);                       // 16 for last tile row
    int tid = threadIdx.x;

    for (int i = tid; i < TH * TW; i += BLK) lkey[i] = 0ULL;
    __syncthreads();

    // source window: all |disp|<=M_ sources whose clipped target lands in tile.
    // wx0 is a multiple of 64 -> 16B-aligned float4 rows. Interior window width
    // is exactly 256 = 64 lanes x float4; 512 threads = 8 rows per sweep.
    int wy0 = max(0, ty0 - M_), wy1 = min(H_, ty0 + th_eff + M_);
    int wx0 = max(0, tx0 - M_), wx1 = min(W_, tx0 + TW + M_);
    const float* fx_p = flow + (size_t)n * 2 * HW;
    const float* fy_p = fx_p + HW;

    int x4   = wx0 + ((tid & 63) << 2);                   // this lane's column
    int rowg = tid >> 6;                                  // 0..7
    if (x4 < wx1) {
        #pragma unroll 2
        for (int y = wy0 + rowg; y < wy1; y += 8) {
            int pbase = y * W_ + x4;
            vf4 fx4 = *(const vf4*)(fx_p + pbase);
            vf4 fy4 = *(const vf4*)(fy_p + pbase);
            float fxs[4] = {fx4.x, fx4.y, fx4.z, fx4.w};
            float fys[4] = {fy4.x, fy4.y, fy4.z, fy4.w};
            #pragma unroll
            for (int i = 0; i < 4; ++i) {
                float fx = fxs[i], fy = fys[i];
                int wx = x4 + i + (int)fx;
                int wy = y + (int)fy;
                wx = min(max(wx, 0), W_ - 1);
                wy = min(max(wy, 0), H_ - 1);
                int lx = wx - tx0, ly = wy - ty0;
                if ((unsigned)lx < (unsigned)TW && (unsigned)ly < (unsigned)th_eff) {
                    atomicMax(&lkey[ly * TW + lx], make_key(fx, fy, pbase + i));
                }
            }
        }
    }
    __syncthreads();

    // apply this batch's outliers (|disp|>M_). Duplicates with the window pass
    // are harmless (same key, max is idempotent). List is ~2.6K entries, L2-hot.
    unsigned long long craw = ocnt[(size_t)n * CSTRIDE];
    int cnt = (int)(craw > (unsigned long long)OSEG ? OSEG : craw);
    const Outlier* seg = olist + n * OSEG;
    for (int o = tid; o < cnt; o += BLK) {
        Outlier e = seg[o];
        int ey = e.tgt / W_, ex = e.tgt - ey * W_;
        int lx = ex - tx0, ly = ey - ty0;
        if ((unsigned)lx < (unsigned)TW && (unsigned)ly < (unsigned)th_eff)
            atomicMax(&lkey[ly * TW + lx], e.key);
    }
    __syncthreads();

    // gather winners' pixels and write the tile (coalesced, nontemporal).
    const float* img_n = image + (size_t)n * C_ * HW;
    float* out_n = out + (size_t)n * C_ * HW;
    int q4 = th_eff * (TW / 4);                           // float4 groups in tile
    for (int s = tid; s < q4; s += BLK) {
        int r = s >> 5;                                   // TW/4 == 32
        int cg = s & 31;
        int lp = r * TW + cg * 4;
        unsigned long long k0 = lkey[lp],     k1 = lkey[lp + 1];
        unsigned long long k2 = lkey[lp + 2], k3 = lkey[lp + 3];
        int s0 = (int)(unsigned int)(k0 & 0xffffffffULL) - 1;
        int s1 = (int)(unsigned int)(k1 & 0xffffffffULL) - 1;
        int s2 = (int)(unsigned int)(k2 & 0xffffffffULL) - 1;
        int s3 = (int)(unsigned int)(k3 & 0xffffffffULL) - 1;
        int op = (ty0 + r) * W_ + tx0 + cg * 4;
        #pragma unroll
        for (int c = 0; c < C_; ++c) {
            const float* pl = img_n + (size_t)c * HW;
            vf4 o;
            o.x = k0 ? pl[s0] : 0.0f;
            o.y = k1 ? pl[s1] : 0.0f;
            o.z = k2 ? pl[s2] : 0.0f;
            o.w = k3 ? pl[s3] : 0.0f;
            __builtin_nontemporal_store(o, (vf4*)(out_n + (size_t)c * HW + op));
        }
    }
}

extern "C" void kernel_launch(void* const* d_in, const int* in_sizes, int n_in,
                              void* d_out, int out_size, void* d_ws, size_t ws_size,
                              hipStream_t stream) {
    const float* image = (const float*)d_in[0];
    const float* flow  = (const float*)d_in[1];
    float* out = (float*)d_out;

    unsigned long long* ocnt = (unsigned long long*)d_ws;  // 8 counters, 128B apart
    Outlier* olist = (Outlier*)((char*)d_ws + 1024);       // 8 x OSEG entries

    (void)hipMemsetAsync(ocnt, 0, 1024, stream);

    int k0_blocks = (N_ * HW / 4) / 256;                   // 7200
    outlier_kernel<<<k0_blocks, 256, 0, stream>>>(flow, ocnt, olist);

    warp_tile_kernel<<<N_ * NTX * NTY, BLK, 0, stream>>>(  // 960 blocks, 1D
        image, flow, ocnt, olist, out);
}

// Round 3
// 288.628 us; speedup vs baseline: 1.6253x; 1.0304x over previous
//
#include <hip/hip_runtime.h>
#include <cstdint>

// Problem constants (from reference): N=8, C=3, H=720, W=1280
constexpr int N_ = 8;
constexpr int C_ = 3;
constexpr int H_ = 720;
constexpr int W_ = 1280;
constexpr int HW = H_ * W_;

constexpr int TW = 128;          // target tile width  (cols)
constexpr int TH = 64;           // target tile height (rows)
constexpr int M_ = 64;           // max handled |trunc(disp)|; beyond -> outlier list
                                 // flow ~ N(0,20): P(|d|>64) ~ 2*Phi(-3.25) => ~2.6K outliers/batch
constexpr int NTX = W_ / TW;                 // 10
constexpr int NTY = (H_ + TH - 1) / TH;      // 12 (last tile = 16 rows)
constexpr int BLK = 1024;        // 2 blocks/CU (64KB LDS each) = 2048 thr = 100% occ
constexpr int OSEG = 16384;      // per-batch outlier capacity (~6x expected)
constexpr int SCAP = 128;        // per-block LDS staging capacity (expected ~3/block)
constexpr int CSTRIDE = 16;      // ULLs between per-batch counters (128 B: own L2 line)
constexpr int BPB = HW / 1024;   // K0 blocks per batch = 900 (exact)

typedef float vf4 __attribute__((ext_vector_type(4)));

struct Outlier { unsigned long long key; int tgt; int pad; };  // 16 B

// key = (bits(v) << 32) | (p+1);  v = fx*fx+fy*fy >= 0 so IEEE bits preserve
// order; low 32 bits implement "larger source index wins ties" (reference's
// stable ascending argsort -> max rank wins). key==0 <=> hole.
__device__ __forceinline__ unsigned long long make_key(float fx, float fy, int p) {
    // exact mul-mul-add in fp32, no FMA contraction (must match numpy bits)
    float v = __fadd_rn(__fmul_rn(fx, fx), __fmul_rn(fy, fy));
    return ((unsigned long long)__float_as_uint(v) << 32) | (unsigned int)(p + 1);
}

// K0: collect rare large-displacement sources into per-batch compact lists.
// Per-block LDS aggregation -> ONE global atomicAdd per block (900/batch,
// counters on separate 128B lines). Round-1 lesson: per-lane device atomics
// on a shared line serialized at ~10ns each (20K outliers -> 210us).
__global__ __launch_bounds__(256) void outlier_kernel(
    const float* __restrict__ flow,
    unsigned long long* __restrict__ ocnt,
    Outlier* __restrict__ olist) {
    __shared__ unsigned int bcnt;
    __shared__ unsigned long long gbase;
    __shared__ unsigned long long skey[SCAP];
    __shared__ int stgt[SCAP];
    if (threadIdx.x == 0) bcnt = 0;
    __syncthreads();

    int n  = blockIdx.x / BPB;                    // batch-pure blocks (900 each)
    int p0 = (blockIdx.x - n * BPB) * 1024 + threadIdx.x * 4;
    const float* f = flow + (size_t)n * 2 * HW;
    vf4 fx4 = *(const vf4*)(f + p0);
    vf4 fy4 = *(const vf4*)(f + HW + p0);
    float fxs[4] = {fx4.x, fx4.y, fx4.z, fx4.w};
    float fys[4] = {fy4.x, fy4.y, fy4.z, fy4.w};
    int y = p0 / W_;
    int x0 = p0 - y * W_;                         // p0 mult of 4, W%4==0: same row
    #pragma unroll
    for (int i = 0; i < 4; ++i) {
        int dx = (int)fxs[i];                     // trunc toward zero == astype(int32)
        int dy = (int)fys[i];
        if (dx > M_ || dx < -M_ || dy > M_ || dy < -M_) {
            int wx = min(max(x0 + i + dx, 0), W_ - 1);
            int wy = min(max(y + dy, 0), H_ - 1);
            unsigned long long key = make_key(fxs[i], fys[i], p0 + i);
            int tgt = wy * W_ + wx;
            unsigned int s = atomicAdd(&bcnt, 1u);
            if (s < (unsigned)SCAP) {
                skey[s] = key; stgt[s] = tgt;
            } else {                              // adversarial-data spill path
                unsigned long long o = atomicAdd(&ocnt[(size_t)n * CSTRIDE], 1ULL);
                if (o < (unsigned long long)OSEG) {
                    Outlier e; e.key = key; e.tgt = tgt; e.pad = 0;
                    olist[n * OSEG + (int)o] = e;
                }
            }
        }
    }
    __syncthreads();
    unsigned int c = bcnt > (unsigned)SCAP ? (unsigned)SCAP : bcnt;
    if (threadIdx.x == 0)
        gbase = c ? atomicAdd(&ocnt[(size_t)n * CSTRIDE], (unsigned long long)c)
                  : 0ULL;
    __syncthreads();
    for (unsigned int i = threadIdx.x; i < c; i += 256) {
        unsigned long long o = gbase + i;
        if (o < (unsigned long long)OSEG) {
            Outlier e; e.key = skey[i]; e.tgt = stgt[i]; e.pad = 0;
            olist[n * OSEG + (int)o] = e;
        }
    }
}

// K1: per target-tile — scan source window (tile +- M_), resolve winners via
// LDS atomicMax, apply outliers, gather image, write out.
// Block remap: n = bid&7, tile = bid>>3 (row-major). Under the round-robin
// block->XCD dispatch this pins one batch per XCD and walks its tiles in
// row-major order: one tile-row's flow window (192 x 1280 x 8B ~ 2MB) fits
// the 4MB per-XCD L2 (round 2: FETCH 506->98 MB confirmed).
// 1024 threads/block: 2 blocks/CU x 64KB LDS -> 2048 thr/CU = 8 waves/SIMD
// (round 2 was 512thr -> 4 waves/SIMD -> latency-bound at 35% occupancy).
__global__ __launch_bounds__(BLK, 8) void warp_tile_kernel(
    const float* __restrict__ image,
    const float* __restrict__ flow,
    const unsigned long long* __restrict__ ocnt,
    const Outlier* __restrict__ olist,
    float* __restrict__ out) {
    __shared__ unsigned long long lkey[TH * TW];          // 64 KB
    int bid = blockIdx.x;
    int n    = bid & 7;                                   // N_ == 8 == #XCDs
    int tile = bid >> 3;                                  // 0..119, row-major
    int tyi = tile / NTX;
    int txi = tile - tyi * NTX;
    int tx0 = txi * TW;
    int ty0 = tyi * TH;
    int th_eff = min(TH, H_ - ty0);                       // 16 for last tile row
    int tid = threadIdx.x;

    for (int i = tid; i < TH * TW; i += BLK) lkey[i] = 0ULL;
    __syncthreads();

    // source window: all |disp|<=M_ sources whose clipped target lands in tile.
    // wx0 is a multiple of 64 -> 16B-aligned float4 rows. Interior window width
    // is exactly 256 = 64 lanes x float4; 1024 threads = 16 rows per sweep.
    int wy0 = max(0, ty0 - M_), wy1 = min(H_, ty0 + th_eff + M_);
    int wx0 = max(0, tx0 - M_), wx1 = min(W_, tx0 + TW + M_);
    const float* fx_p = flow + (size_t)n * 2 * HW;
    const float* fy_p = fx_p + HW;

    int x4   = wx0 + ((tid & 63) << 2);                   // this lane's column
    int rowg = tid >> 6;                                  // 0..15
    if (x4 < wx1) {
        #pragma unroll 2
        for (int y = wy0 + rowg; y < wy1; y += 16) {
            int pbase = y * W_ + x4;
            vf4 fx4 = *(const vf4*)(fx_p + pbase);
            vf4 fy4 = *(const vf4*)(fy_p + pbase);
            float fxs[4] = {fx4.x, fx4.y, fx4.z, fx4.w};
            float fys[4] = {fy4.x, fy4.y, fy4.z, fy4.w};
            #pragma unroll
            for (int i = 0; i < 4; ++i) {
                float fx = fxs[i], fy = fys[i];
                int wx = x4 + i + (int)fx;
                int wy = y + (int)fy;
                wx = min(max(wx, 0), W_ - 1);
                wy = min(max(wy, 0), H_ - 1);
                int lx = wx - tx0, ly = wy - ty0;
                if ((unsigned)lx < (unsigned)TW && (unsigned)ly < (unsigned)th_eff) {
                    atomicMax(&lkey[ly * TW + lx], make_key(fx, fy, pbase + i));
                }
            }
        }
    }
    __syncthreads();

    // apply this batch's outliers (|disp|>M_). Duplicates with the window pass
    // are harmless (same key, max is idempotent). List is ~2.6K entries, L2-hot.
    unsigned long long craw = ocnt[(size_t)n * CSTRIDE];
    int cnt = (int)(craw > (unsigned long long)OSEG ? OSEG : craw);
    const Outlier* seg = olist + n * OSEG;
    for (int o = tid; o < cnt; o += BLK) {
        Outlier e = seg[o];
        int ey = e.tgt / W_, ex = e.tgt - ey * W_;
        int lx = ex - tx0, ly = ey - ty0;
        if ((unsigned)lx < (unsigned)TW && (unsigned)ly < (unsigned)th_eff)
            atomicMax(&lkey[ly * TW + lx], e.key);
    }
    __syncthreads();

    // gather winners' pixels and write the tile (coalesced, nontemporal).
    const float* img_n = image + (size_t)n * C_ * HW;
    float* out_n = out + (size_t)n * C_ * HW;
    int q4 = th_eff * (TW / 4);                           // float4 groups in tile
    for (int s = tid; s < q4; s += BLK) {
        int r = s >> 5;                                   // TW/4 == 32
        int cg = s & 31;
        int lp = r * TW + cg * 4;
        unsigned long long k0 = lkey[lp],     k1 = lkey[lp + 1];
        unsigned long long k2 = lkey[lp + 2], k3 = lkey[lp + 3];
        int s0 = (int)(unsigned int)(k0 & 0xffffffffULL) - 1;
        int s1 = (int)(unsigned int)(k1 & 0xffffffffULL) - 1;
        int s2 = (int)(unsigned int)(k2 & 0xffffffffULL) - 1;
        int s3 = (int)(unsigned int)(k3 & 0xffffffffULL) - 1;
        int op = (ty0 + r) * W_ + tx0 + cg * 4;
        #pragma unroll
        for (int c = 0; c < C_; ++c) {
            const float* pl = img_n + (size_t)c * HW;
            vf4 o;
            o.x = k0 ? pl[s0] : 0.0f;
            o.y = k1 ? pl[s1] : 0.0f;
            o.z = k2 ? pl[s2] : 0.0f;
            o.w = k3 ? pl[s3] : 0.0f;
            __builtin_nontemporal_store(o, (vf4*)(out_n + (size_t)c * HW + op));
        }
    }
}

extern "C" void kernel_launch(void* const* d_in, const int* in_sizes, int n_in,
                              void* d_out, int out_size, void* d_ws, size_t ws_size,
                              hipStream_t stream) {
    const float* image = (const float*)d_in[0];
    const float* flow  = (const float*)d_in[1];
    float* out = (float*)d_out;

    unsigned long long* ocnt = (unsigned long long*)d_ws;  // 8 counters, 128B apart
    Outlier* olist = (Outlier*)((char*)d_ws + 1024);       // 8 x OSEG entries

    (void)hipMemsetAsync(ocnt, 0, 1024, stream);

    int k0_blocks = (N_ * HW / 4) / 256;                   // 7200
    outlier_kernel<<<k0_blocks, 256, 0, stream>>>(flow, ocnt, olist);

    warp_tile_kernel<<<N_ * NTX * NTY, BLK, 0, stream>>>(  // 960 blocks, 1D
        image, flow, ocnt, olist, out);
}